// Round 15
// baseline (249.273 us; speedup 1.0000x reference)
//
#include <hip/hip_runtime.h>
#include <hip/hip_bf16.h>
#include <hip/hip_cooperative_groups.h>

namespace cg = cooperative_groups;

#define B_ 2
#define H_ 8
#define L_ 4096
#define D_ 64
#define NB_ 64
#define TOPK_ 16
#define BH_ 16

typedef __bf16 bf16x8 __attribute__((ext_vector_type(8)));
typedef float f32x4 __attribute__((ext_vector_type(4)));

#if __has_builtin(__builtin_amdgcn_exp2f)
#define EXP2(x) __builtin_amdgcn_exp2f(x)
#else
#define EXP2(x) exp2f(x)
#endif

__device__ __forceinline__ void async_copy16(void* lds, const void* g) {
  __builtin_amdgcn_global_load_lds(
      (const __attribute__((address_space(1))) void*)g,
      (__attribute__((address_space(3))) void*)lds, 16, 0, 0);
}

// ---------------------------------------------------------------------------
// prep_body: k-image (R8 XOR-swizzled) + k block mean (block_means' exact
// layout & summation order -> pk bit-identical) + v-image (V^T, kpos-
// permuted, XOR-swizzled).  One source block per call.  smem >= 25.6 KB.
// ---------------------------------------------------------------------------
__device__ __forceinline__ void prep_body(
    int blk, int tid,
    const float* __restrict__ k, const float* __restrict__ v,
    float* __restrict__ pk, __bf16* __restrict__ kswz,
    __bf16* __restrict__ vtswz, char* smem) {
  float (*s_kf)[64] = reinterpret_cast<float(*)[64]>(smem);          // 16384 B
  float* bufk = reinterpret_cast<float*>(smem + 16384);              // 1024 B
  __bf16* s_vt = reinterpret_cast<__bf16*>(smem + 17408);            // 8192 B

  const int srow = tid >> 2;           // key row 0..63
  const int sc16 = (tid & 3) * 16;     // d col base

  const float* ks = k + (size_t)blk * 4096 + srow * 64 + sc16;
  const float* vs = v + (size_t)blk * 4096 + srow * 64 + sc16;
  float kf[16], vf[16];
#pragma unroll
  for (int h = 0; h < 4; h++) {
    float4 t4 = *(const float4*)(ks + h * 4);
    kf[h * 4 + 0] = t4.x; kf[h * 4 + 1] = t4.y; kf[h * 4 + 2] = t4.z; kf[h * 4 + 3] = t4.w;
    *(float4*)&s_kf[srow][sc16 + h * 4] = t4;
  }
#pragma unroll
  for (int h = 0; h < 4; h++) {
    float4 u4 = *(const float4*)(vs + h * 4);
    vf[h * 4 + 0] = u4.x; vf[h * 4 + 1] = u4.y; vf[h * 4 + 2] = u4.z; vf[h * 4 + 3] = u4.w;
  }

  __bf16* gk = kswz + (size_t)blk * 4096;
#pragma unroll
  for (int h = 0; h < 2; h++) {
    int c8 = (sc16 >> 3) + h;
    bf16x8 kw;
#pragma unroll
    for (int j = 0; j < 8; j++) kw[j] = (__bf16)kf[h * 8 + j];
    *(bf16x8*)(gk + srow * 64 + ((c8 ^ (srow & 7)) << 3)) = kw;
  }

  const int kpos = (srow & 32) + ((srow >> 2) & 3) * 8 + ((srow >> 4) & 1) * 4 + (srow & 3);
#pragma unroll
  for (int i = 0; i < 16; i++) {
    int d = sc16 + i;
    s_vt[d * 64 + (kpos ^ ((d & 7) << 3))] = (__bf16)vf[i];
  }
  __syncthreads();

  // k mean: thread (d,g) sums rows g*16+i sequentially (block_means order)
  const int d = tid & 63, g = tid >> 6;
  float sk = 0.f;
#pragma unroll
  for (int i = 0; i < 16; i++) sk += s_kf[g * 16 + i][d];
  bufk[g * 64 + d] = sk;

  // v image copy-out (s_vt ready after the sync above)
  __bf16* gv = vtswz + (size_t)blk * 4096;
  *(bf16x8*)(gv + tid * 8)        = *(const bf16x8*)(s_vt + tid * 8);
  *(bf16x8*)(gv + 2048 + tid * 8) = *(const bf16x8*)(s_vt + 2048 + tid * 8);

  __syncthreads();
  if (g == 0) {
    float tk = bufk[0 * 64 + d] + bufk[1 * 64 + d] + bufk[2 * 64 + d] + bufk[3 * 64 + d];
    pk[(size_t)blk * 64 + d] = tk * (1.f / 64.f);
  }
}

// ---------------------------------------------------------------------------
// attn_body: R14 sparse_attn_fast body (prologue A: q-mean exact order;
// prologue B: blockmap selection exact replication; main loop: KV LDS
// double-buffer, counted vmcnt(4) + 2 raw s_barriers, P in-register,
// no max tracking).  Q fragments hoisted above the prologues.
// ---------------------------------------------------------------------------
__device__ __forceinline__ void attn_body(
    int blk, int tid,
    const float* __restrict__ q, const __bf16* __restrict__ kswz,
    const __bf16* __restrict__ vtswz, const float* __restrict__ pk,
    float* __restrict__ out, char* smem) {
  const int bh = blk >> 6, m = blk & 63;
  const int lane = tid & 63;
  const int w = tid >> 6;
  const int l16 = lane & 15, lhi = lane >> 4;

  __bf16 (*KV)[8192] = reinterpret_cast<__bf16(*)[8192]>(smem);
  float (*s_qf)[68] = reinterpret_cast<float(*)[68]>(smem);           // 17408 B
  float* bufq  = reinterpret_cast<float*>(smem + 17408);              // 1024 B
  float (*s_pk)[65] = reinterpret_cast<float(*)[65]>(smem);           // 16640 B
  float* s_pqr = reinterpret_cast<float*>(smem + 16640);              // 256 B
  float* s_km  = reinterpret_cast<float*>(smem + 16896);              // 256 B
  float* s_sc  = reinterpret_cast<float*>(smem + 17152);              // 256 B
  int*   s_lut = reinterpret_cast<int*>(smem + 18432);                // 64 B

  const size_t base = (size_t)bh * L_ * D_;

  // ---- Q B-fragments (hoisted: global loads hide under prologue) ----
  const float QSC = 0.125f * 1.44269504088896340736f;
  bf16x8 qf[2];
  {
    const float* qrow = q + base + (size_t)(m * 64 + w * 16 + l16) * D_;
#pragma unroll
    for (int s = 0; s < 2; s++) {
      const float* p0 = qrow + s * 32 + lhi * 8;
      float4 a = *(const float4*)p0;
      float4 b = *(const float4*)(p0 + 4);
      bf16x8 f;
      f[0] = (__bf16)(a.x * QSC); f[1] = (__bf16)(a.y * QSC);
      f[2] = (__bf16)(a.z * QSC); f[3] = (__bf16)(a.w * QSC);
      f[4] = (__bf16)(b.x * QSC); f[5] = (__bf16)(b.y * QSC);
      f[6] = (__bf16)(b.z * QSC); f[7] = (__bf16)(b.w * QSC);
      qf[s] = f;
    }
  }

  // ---- prologue A: pq row m from q (block_means' exact order) ----
  {
    const float* qsrc = q + base + (size_t)(m * 64) * D_;
    const int r = tid >> 2, c = (tid & 3) * 16;
    const float* qs = qsrc + r * 64 + c;
#pragma unroll
    for (int h = 0; h < 4; h++)
      *(float4*)&s_qf[r][c + h * 4] = *(const float4*)(qs + h * 4);
  }
  __syncthreads();
  {
    const int d = tid & 63, g = tid >> 6;
    float sq = 0.f;
#pragma unroll
    for (int i = 0; i < 16; i++) sq += s_qf[g * 16 + i][d];
    bufq[g * 64 + d] = sq;
  }
  __syncthreads();
  if (tid < 64) {   // g==0
    float tq = bufq[0 * 64 + tid] + bufq[1 * 64 + tid] + bufq[2 * 64 + tid] + bufq[3 * 64 + tid];
    s_pqr[tid] = tq * (1.f / 64.f);
  }
  __syncthreads();

  // ---- prologue B: blockmap selection for row m (EXACT replication) ----
  {
    const float* pkb = pk + (size_t)bh * 4096;
#pragma unroll
    for (int i = 0; i < 16; i++) {
      int idx = i * 256 + tid;
      s_pk[idx >> 6][idx & 63] = pkb[idx];
    }
    __syncthreads();
    if (tid < 64) {
      float s = 0.f;
#pragma unroll 8
      for (int r = 0; r < 64; r++) s += s_pk[r][tid];
      s_km[tid] = s * (1.f / 64.f);
    }
    __syncthreads();
    float sc = 0.f;
#pragma unroll 8
    for (int d2 = 0; d2 < 64; ++d2)
      sc += s_pqr[d2] * (s_pk[lane][d2] - s_km[d2]);
    s_sc[lane] = sc;
    __syncthreads();
    int rank = 0;
#pragma unroll 8
    for (int j = 0; j < 64; j++) {
      float o = s_sc[j];
      rank += (o > sc) || (o == sc && j < lane);
    }
    if (rank < TOPK_) s_lut[rank] = lane;
    __syncthreads();
  }
  const int myk = s_lut[lane & 15];   // LUT -> registers
  __syncthreads();                    // all s_lut reads done; smem free

  const __bf16* kimg = kswz + (size_t)bh * 64 * 4096;
  const __bf16* vbase = vtswz + (size_t)bh * 64 * 4096;

  auto stage = [&](int b, int kb) {
    const __bf16* gk = kimg + (size_t)kb * 4096;
    const __bf16* gv = vbase + (size_t)kb * 4096;
    async_copy16(&KV[b][0 * 2048 + w * 512], gk + 0 * 2048 + tid * 8);
    async_copy16(&KV[b][1 * 2048 + w * 512], gk + 1 * 2048 + tid * 8);
    async_copy16(&KV[b][4096 + 0 * 2048 + w * 512], gv + 0 * 2048 + tid * 8);
    async_copy16(&KV[b][4096 + 1 * 2048 + w * 512], gv + 1 * 2048 + tid * 8);
  };

  stage(0, __shfl(myk, 0, 64));

  f32x4 acc_o[4];
#pragma unroll
  for (int i = 0; i < 4; i++) acc_o[i] = (f32x4){0.f, 0.f, 0.f, 0.f};
  float l_run = 0.f;

  for (int it = 0; it < TOPK_; ++it) {
    const int cur = it & 1;
    if (it + 1 < TOPK_) {
      stage(cur ^ 1, __shfl(myk, it + 1, 64));
      asm volatile("s_waitcnt vmcnt(4)" ::: "memory");   // stage(it) landed
    } else {
      asm volatile("s_waitcnt vmcnt(0)" ::: "memory");
    }
    __builtin_amdgcn_s_barrier();          // B1: everyone's stage(it) complete
    __builtin_amdgcn_sched_barrier(0);     // nothing crosses upward

    const __bf16* Kl = &KV[cur][0];
    const __bf16* Vt = &KV[cur][4096];

    // ---- S^T = K @ Q^T (log2 units): accs[ct][r] = S[16ct+4lhi+r][l16] ----
    f32x4 accs[4];
#pragma unroll
    for (int x = 0; x < 4; x++) accs[x] = (f32x4){0.f, 0.f, 0.f, 0.f};
    __builtin_amdgcn_s_setprio(1);
#pragma unroll
    for (int ct = 0; ct < 4; ct++) {
      const int key = ct * 16 + l16;
#pragma unroll
      for (int s = 0; s < 2; s++) {
        const int c8 = s * 4 + lhi;
        bf16x8 bk = *(const bf16x8*)&Kl[key * 64 + ((c8 ^ (key & 7)) << 3)];
        accs[ct] = __builtin_amdgcn_mfma_f32_16x16x32_bf16(bk, qf[s], accs[ct], 0, 0, 0);
      }
    }
    __builtin_amdgcn_s_setprio(0);

    // ---- P = exp2(S) straight into PV A-fragments (no max tracking) ----
    bf16x8 pa0, pa1;
    float ls0 = 0.f, ls1 = 0.f;
#pragma unroll
    for (int j = 0; j < 8; j++) {
      float e0 = EXP2(accs[(j >> 2)][j & 3]);
      float e1 = EXP2(accs[2 + (j >> 2)][j & 3]);
      pa0[j] = (__bf16)e0; pa1[j] = (__bf16)e1;
      ls0 += e0; ls1 += e1;
    }
    l_run += ls0 + ls1;

    // ---- O += P @ V (V-image columns kpos-ordered, XOR-swizzled) ----
    __builtin_amdgcn_s_setprio(1);
#pragma unroll
    for (int s2 = 0; s2 < 2; s2++) {
      const int c8 = s2 * 4 + lhi;
      const bf16x8 pa = s2 ? pa1 : pa0;
#pragma unroll
      for (int ct2 = 0; ct2 < 4; ct2++) {
        const int d = ct2 * 16 + l16;
        bf16x8 bv = *(const bf16x8*)&Vt[d * 64 + ((c8 ^ (d & 7)) << 3)];
        acc_o[ct2] = __builtin_amdgcn_mfma_f32_16x16x32_bf16(pa, bv, acc_o[ct2], 0, 0, 0);
      }
    }
    __builtin_amdgcn_s_setprio(0);

    __builtin_amdgcn_s_barrier();          // B2: all reads of buf[cur] done
  }

  // ---- epilogue ----
  l_run += __shfl_xor(l_run, 16, 64);
  l_run += __shfl_xor(l_run, 32, 64);
  float rq[4];
#pragma unroll
  for (int r = 0; r < 4; r++)
    rq[r] = 1.f / __shfl(l_run, (lane & 48) | (lhi * 4 + r), 64);

  float* ob = out + base + (size_t)(m * 64 + w * 16) * D_;
#pragma unroll
  for (int ct2 = 0; ct2 < 4; ct2++) {
#pragma unroll
    for (int r = 0; r < 4; r++) {
      const int row = lhi * 4 + r, col = ct2 * 16 + l16;
      ob[(size_t)row * D_ + col] = acc_o[ct2][r] * rq[r];
    }
  }
}

// ---------------------------------------------------------------------------
// Fused cooperative kernel: phase 1 prep -> grid sync -> phase 2 attn.
// ---------------------------------------------------------------------------
__global__ __launch_bounds__(256, 5) void fused_kernel(
    const float* __restrict__ q, const float* __restrict__ k,
    const float* __restrict__ v, float* __restrict__ pk,
    __bf16* __restrict__ kswz, __bf16* __restrict__ vtswz,
    float* __restrict__ out) {
  __shared__ __align__(16) char smem[32768];
  const int bid = blockIdx.x;
  const int tid = threadIdx.x;
  prep_body(bid, tid, k, v, pk, kswz, vtswz, smem);
  __threadfence();
  cg::this_grid().sync();
  const int blk = (bid & 7) * 128 + (bid >> 3);   // T1 XCD swizzle
  attn_body(blk, tid, q, kswz, vtswz, pk, out, smem);
}

// ---------------------------------------------------------------------------
// Two-kernel fast path (R14-equivalent) used if cooperative launch fails.
// ---------------------------------------------------------------------------
__global__ __launch_bounds__(256) void prep_kernel2(
    const float* __restrict__ k, const float* __restrict__ v,
    float* __restrict__ pk, __bf16* __restrict__ kswz,
    __bf16* __restrict__ vtswz) {
  __shared__ __align__(16) char smem[32768];
  prep_body(blockIdx.x, threadIdx.x, k, v, pk, kswz, vtswz, smem);
}

__global__ __launch_bounds__(256, 5) void attn_kernel2(
    const float* __restrict__ q, const __bf16* __restrict__ kswz,
    const __bf16* __restrict__ vtswz, const float* __restrict__ pk,
    float* __restrict__ out) {
  __shared__ __align__(16) char smem[32768];
  const int bid = blockIdx.x;
  const int blk = (bid & 7) * 128 + (bid >> 3);
  attn_body(blk, threadIdx.x, q, kswz, vtswz, pk, out, smem);
}

// ---------------------------------------------------------------------------
// Slow fallback (ws too small): round-2 versions.
// ---------------------------------------------------------------------------
__global__ __launch_bounds__(256) void block_means_kernel(
    const float* __restrict__ q, const float* __restrict__ k,
    float* __restrict__ pq, float* __restrict__ pk) {
  const int blk = blockIdx.x;
  const int bh = blk >> 6, m = blk & 63;
  const int d = threadIdx.x & 63, g = threadIdx.x >> 6;
  const float* qb = q + ((size_t)bh * L_ + m * 64 + g * 16) * D_ + d;
  const float* kb = k + ((size_t)bh * L_ + m * 64 + g * 16) * D_ + d;
  float sq = 0.f, sk = 0.f;
#pragma unroll
  for (int i = 0; i < 16; i++) { sq += qb[(size_t)i * D_]; sk += kb[(size_t)i * D_]; }
  __shared__ float bufq[4][64];
  __shared__ float bufk[4][64];
  bufq[g][d] = sq; bufk[g][d] = sk;
  __syncthreads();
  if (g == 0) {
    float tq = bufq[0][d] + bufq[1][d] + bufq[2][d] + bufq[3][d];
    float tk = bufk[0][d] + bufk[1][d] + bufk[2][d] + bufk[3][d];
    pq[(size_t)blk * 64 + d] = tq * (1.f / 64.f);
    pk[(size_t)blk * 64 + d] = tk * (1.f / 64.f);
  }
}

__global__ __launch_bounds__(256) void blockmap_kernel(
    const float* __restrict__ pq, const float* __restrict__ pk,
    int* __restrict__ lut) {
  const int g = blockIdx.x;
  const int bh = g >> 2, q4 = g & 3;
  const int t = threadIdx.x;
  const int lane = t & 63, w = t >> 6;

  __shared__ float s_pk[64][65];
  __shared__ float s_km[64];
  __shared__ float s_pq[16][64];
  __shared__ float s_sc[4][64];

#pragma unroll
  for (int i = 0; i < 16; i++) {
    int idx = i * 256 + t;
    s_pk[idx >> 6][idx & 63] = pk[(size_t)bh * 4096 + idx];
  }
#pragma unroll
  for (int i = 0; i < 4; i++) {
    int idx = i * 256 + t;
    s_pq[idx >> 6][idx & 63] = pq[(size_t)bh * 4096 + q4 * 1024 + idx];
  }
  __syncthreads();
  if (t < 64) {
    float s = 0.f;
#pragma unroll 8
    for (int r = 0; r < 64; r++) s += s_pk[r][t];
    s_km[t] = s * (1.f / 64.f);
  }
  __syncthreads();

#pragma unroll
  for (int rr = 0; rr < 4; rr++) {
    const int row = w * 4 + rr;
    float sc = 0.f;
#pragma unroll 8
    for (int d2 = 0; d2 < 64; ++d2)
      sc += s_pq[row][d2] * (s_pk[lane][d2] - s_km[d2]);
    s_sc[w][lane] = sc;
    __syncthreads();
    int rank = 0;
#pragma unroll 8
    for (int j = 0; j < 64; j++) {
      float o = s_sc[w][j];
      rank += (o > sc) || (o == sc && j < lane);
    }
    if (rank < TOPK_)
      lut[((size_t)bh * 64 + q4 * 16 + row) * TOPK_ + rank] = lane;
    __syncthreads();
  }
}

__global__ __launch_bounds__(256) void sparse_attn_slow(
    const float* __restrict__ q, const float* __restrict__ k,
    const float* __restrict__ v, const int* __restrict__ lut,
    float* __restrict__ out) {
  const int blk = blockIdx.x;
  const int bh = blk >> 6, m = blk & 63;
  const int tid = threadIdx.x;
  const int lane = tid & 63;
  const int w = tid >> 6;
  const int l16 = lane & 15, lhi = lane >> 4;

  __shared__ __align__(16) __bf16 Kl[64 * 64];
  __shared__ __align__(16) __bf16 Vt[64 * 64];
  __shared__ __align__(16) __bf16 Pl[4][16 * 64];

  const size_t base = (size_t)bh * L_ * D_;

  bf16x8 qf[2];
  {
    const float* qrow = q + base + (size_t)(m * 64 + w * 16 + l16) * D_;
#pragma unroll
    for (int s = 0; s < 2; s++) {
      const float* p0 = qrow + s * 32 + lhi * 8;
      float4 a = *(const float4*)p0;
      float4 b = *(const float4*)(p0 + 4);
      bf16x8 f;
      f[0] = (__bf16)(a.x * 0.125f); f[1] = (__bf16)(a.y * 0.125f);
      f[2] = (__bf16)(a.z * 0.125f); f[3] = (__bf16)(a.w * 0.125f);
      f[4] = (__bf16)(b.x * 0.125f); f[5] = (__bf16)(b.y * 0.125f);
      f[6] = (__bf16)(b.z * 0.125f); f[7] = (__bf16)(b.w * 0.125f);
      qf[s] = f;
    }
  }

  f32x4 acc_o[4];
#pragma unroll
  for (int i = 0; i < 4; i++) acc_o[i] = (f32x4){0.f, 0.f, 0.f, 0.f};
  float m_run[4] = {-__builtin_inff(), -__builtin_inff(), -__builtin_inff(), -__builtin_inff()};
  float l_run[4] = {0.f, 0.f, 0.f, 0.f};

  const int srow = tid >> 2;
  const int sc16 = (tid & 3) * 16;

  for (int it = 0; it < TOPK_; ++it) {
    const int kb = lut[(size_t)blk * TOPK_ + it];
    __syncthreads();
    {
      const float* ks = k + base + (size_t)(kb * 64 + srow) * D_ + sc16;
      const float* vs = v + base + (size_t)(kb * 64 + srow) * D_ + sc16;
      float kf[16], vf[16];
#pragma unroll
      for (int h = 0; h < 4; h++) {
        float4 t4 = *(const float4*)(ks + h * 4);
        kf[h * 4 + 0] = t4.x; kf[h * 4 + 1] = t4.y; kf[h * 4 + 2] = t4.z; kf[h * 4 + 3] = t4.w;
        float4 u4 = *(const float4*)(vs + h * 4);
        vf[h * 4 + 0] = u4.x; vf[h * 4 + 1] = u4.y; vf[h * 4 + 2] = u4.z; vf[h * 4 + 3] = u4.w;
      }
#pragma unroll
      for (int h = 0; h < 2; h++) {
        int c8 = (sc16 >> 3) + h;
        bf16x8 kw;
#pragma unroll
        for (int j = 0; j < 8; j++) kw[j] = (__bf16)kf[h * 8 + j];
        *(bf16x8*)&Kl[srow * 64 + ((c8 ^ (srow & 7)) << 3)] = kw;
      }
#pragma unroll
      for (int i = 0; i < 16; i++) {
        int d = sc16 + i;
        Vt[d * 64 + (srow ^ ((d & 7) << 3))] = (__bf16)vf[i];
      }
    }
    __syncthreads();

    f32x4 accs[4];
#pragma unroll
    for (int i = 0; i < 4; i++) accs[i] = (f32x4){0.f, 0.f, 0.f, 0.f};
#pragma unroll
    for (int ct = 0; ct < 4; ct++) {
      const int key = ct * 16 + l16;
#pragma unroll
      for (int s = 0; s < 2; s++) {
        const int c8 = s * 4 + lhi;
        bf16x8 bk = *(const bf16x8*)&Kl[key * 64 + ((c8 ^ (key & 7)) << 3)];
        accs[ct] = __builtin_amdgcn_mfma_f32_16x16x32_bf16(qf[s], bk, accs[ct], 0, 0, 0);
      }
    }

    float pvals[4][4];
#pragma unroll
    for (int r = 0; r < 4; r++) {
      float mx = fmaxf(fmaxf(accs[0][r], accs[1][r]), fmaxf(accs[2][r], accs[3][r]));
#pragma unroll
      for (int off = 1; off < 16; off <<= 1) mx = fmaxf(mx, __shfl_xor(mx, off, 64));
      const float mnew = fmaxf(m_run[r], mx);
      const float scale = __expf(m_run[r] - mnew);
      float rs = 0.f;
#pragma unroll
      for (int ct = 0; ct < 4; ct++) {
        float e = __expf(accs[ct][r] - mnew);
        pvals[ct][r] = e; rs += e;
      }
#pragma unroll
      for (int off = 1; off < 16; off <<= 1) rs += __shfl_xor(rs, off, 64);
      l_run[r] = l_run[r] * scale + rs;
      m_run[r] = mnew;
#pragma unroll
      for (int ct = 0; ct < 4; ct++) acc_o[ct][r] *= scale;
    }

#pragma unroll
    for (int ct = 0; ct < 4; ct++) {
#pragma unroll
      for (int r = 0; r < 4; r++) {
        const int row = lhi * 4 + r, col = ct * 16 + l16;
        Pl[w][row * 64 + (col ^ ((row & 7) << 3))] = (__bf16)pvals[ct][r];
      }
    }
#pragma unroll
    for (int s = 0; s < 2; s++) {
      const int c8 = s * 4 + lhi;
      bf16x8 pa = *(const bf16x8*)&Pl[w][l16 * 64 + ((c8 ^ (l16 & 7)) << 3)];
#pragma unroll
      for (int ct2 = 0; ct2 < 4; ct2++) {
        const int d = ct2 * 16 + l16;
        bf16x8 bv = *(const bf16x8*)&Vt[d * 64 + ((c8 ^ (d & 7)) << 3)];
        acc_o[ct2] = __builtin_amdgcn_mfma_f32_16x16x32_bf16(pa, bv, acc_o[ct2], 0, 0, 0);
      }
    }
  }

  float* ob = out + base + (size_t)(m * 64 + w * 16) * D_;
#pragma unroll
  for (int ct2 = 0; ct2 < 4; ct2++) {
#pragma unroll
    for (int r = 0; r < 4; r++) {
      const int row = lhi * 4 + r, col = ct2 * 16 + l16;
      ob[(size_t)row * D_ + col] = acc_o[ct2][r] / l_run[r];
    }
  }
}

extern "C" void kernel_launch(void* const* d_in, const int* in_sizes, int n_in,
                              void* d_out, int out_size, void* d_ws, size_t ws_size,
                              hipStream_t stream) {
  const float* q = (const float*)d_in[0];
  const float* k = (const float*)d_in[1];
  const float* v = (const float*)d_in[2];
  float* out = (float*)d_out;

  // ws layout: pq (256KB) | pk (256KB) | lut (64KB) | Kswz (8MB) | Vtswz (8MB)
  float* pq = (float*)d_ws;
  float* pk = pq + (size_t)BH_ * NB_ * D_;
  int*   lut = (int*)(pk + (size_t)BH_ * NB_ * D_);
  char*  extra = (char*)(lut + (size_t)BH_ * NB_ * TOPK_);
  __bf16* kswz = (__bf16*)extra;
  __bf16* vtswz = kswz + (size_t)BH_ * NB_ * 4096;

  const size_t needed = (size_t)((char*)(vtswz + (size_t)BH_ * NB_ * 4096) - (char*)d_ws);
  const bool fast = ws_size >= needed;

  if (fast) {
    void* args[] = {(void*)&q, (void*)&k, (void*)&v, (void*)&pk,
                    (void*)&kswz, (void*)&vtswz, (void*)&out};
    hipError_t e = hipLaunchCooperativeKernel((void*)fused_kernel,
                                              dim3(BH_ * NB_), dim3(256),
                                              args, 0, stream);
    if (e != hipSuccess) {
      (void)hipGetLastError();   // clear; fall back to the two-kernel path
      hipLaunchKernelGGL(prep_kernel2, dim3(BH_ * NB_), dim3(256), 0, stream,
                         k, v, pk, kswz, vtswz);
      hipLaunchKernelGGL(attn_kernel2, dim3(BH_ * NB_), dim3(256), 0, stream,
                         q, kswz, vtswz, pk, out);
    }
  } else {
    hipLaunchKernelGGL(block_means_kernel, dim3(BH_ * NB_), dim3(256), 0, stream, q, k, pq, pk);
    hipLaunchKernelGGL(blockmap_kernel, dim3(BH_ * 4), dim3(256), 0, stream, pq, pk, lut);
    hipLaunchKernelGGL(sparse_attn_slow, dim3(BH_ * NB_), dim3(256), 0, stream, q, k, v, lut, out);
  }
}

// Round 16
// 44.674 us; speedup vs baseline: 5.5798x; 5.5798x over previous
//
#include <hip/hip_runtime.h>
#include <hip/hip_bf16.h>

#define B_ 2
#define H_ 8
#define L_ 4096
#define D_ 64
#define NB_ 64
#define TOPK_ 16
#define BH_ 16

typedef __bf16 bf16x8 __attribute__((ext_vector_type(8)));
typedef float f32x4 __attribute__((ext_vector_type(4)));

#if __has_builtin(__builtin_amdgcn_exp2f)
#define EXP2(x) __builtin_amdgcn_exp2f(x)
#else
#define EXP2(x) exp2f(x)
#endif

__device__ __forceinline__ void async_copy16(void* lds, const void* g) {
  __builtin_amdgcn_global_load_lds(
      (const __attribute__((address_space(1))) void*)g,
      (__attribute__((address_space(3))) void*)lds, 16, 0, 0);
}

// ---------------------------------------------------------------------------
// prep_body: k-image (R8 XOR-swizzled) + k block mean (block_means' exact
// layout & summation order -> pk bit-identical) + v-image (V^T, kpos-
// permuted, XOR-swizzled).  One source block per call.
// ---------------------------------------------------------------------------
__device__ __forceinline__ void prep_body(
    int blk, int tid,
    const float* __restrict__ k, const float* __restrict__ v,
    float* __restrict__ pk, __bf16* __restrict__ kswz,
    __bf16* __restrict__ vtswz, char* smem) {
  float (*s_kf)[64] = reinterpret_cast<float(*)[64]>(smem);          // 16384 B
  float* bufk = reinterpret_cast<float*>(smem + 16384);              // 1024 B
  __bf16* s_vt = reinterpret_cast<__bf16*>(smem + 17408);            // 8192 B

  const int srow = tid >> 2;           // key row 0..63
  const int sc16 = (tid & 3) * 16;     // d col base

  const float* ks = k + (size_t)blk * 4096 + srow * 64 + sc16;
  const float* vs = v + (size_t)blk * 4096 + srow * 64 + sc16;
  float kf[16], vf[16];
#pragma unroll
  for (int h = 0; h < 4; h++) {
    float4 t4 = *(const float4*)(ks + h * 4);
    kf[h * 4 + 0] = t4.x; kf[h * 4 + 1] = t4.y; kf[h * 4 + 2] = t4.z; kf[h * 4 + 3] = t4.w;
    *(float4*)&s_kf[srow][sc16 + h * 4] = t4;
  }
#pragma unroll
  for (int h = 0; h < 4; h++) {
    float4 u4 = *(const float4*)(vs + h * 4);
    vf[h * 4 + 0] = u4.x; vf[h * 4 + 1] = u4.y; vf[h * 4 + 2] = u4.z; vf[h * 4 + 3] = u4.w;
  }

  __bf16* gk = kswz + (size_t)blk * 4096;
#pragma unroll
  for (int h = 0; h < 2; h++) {
    int c8 = (sc16 >> 3) + h;
    bf16x8 kw;
#pragma unroll
    for (int j = 0; j < 8; j++) kw[j] = (__bf16)kf[h * 8 + j];
    *(bf16x8*)(gk + srow * 64 + ((c8 ^ (srow & 7)) << 3)) = kw;
  }

  const int kpos = (srow & 32) + ((srow >> 2) & 3) * 8 + ((srow >> 4) & 1) * 4 + (srow & 3);
#pragma unroll
  for (int i = 0; i < 16; i++) {
    int d = sc16 + i;
    s_vt[d * 64 + (kpos ^ ((d & 7) << 3))] = (__bf16)vf[i];
  }
  __syncthreads();

  // k mean: thread (d,g) sums rows g*16+i sequentially (block_means order)
  const int d = tid & 63, g = tid >> 6;
  float sk = 0.f;
#pragma unroll
  for (int i = 0; i < 16; i++) sk += s_kf[g * 16 + i][d];
  bufk[g * 64 + d] = sk;

  // v image copy-out (s_vt ready after the sync above)
  __bf16* gv = vtswz + (size_t)blk * 4096;
  *(bf16x8*)(gv + tid * 8)        = *(const bf16x8*)(s_vt + tid * 8);
  *(bf16x8*)(gv + 2048 + tid * 8) = *(const bf16x8*)(s_vt + 2048 + tid * 8);

  __syncthreads();
  if (g == 0) {
    float tk = bufk[0 * 64 + d] + bufk[1 * 64 + d] + bufk[2 * 64 + d] + bufk[3 * 64 + d];
    pk[(size_t)blk * 64 + d] = tk * (1.f / 64.f);
  }
}

// ---------------------------------------------------------------------------
// attn_body: prologue A (q-mean, block_means' exact order), prologue B
// (blockmap selection, exact replication), main loop (KV LDS double-buffer,
// counted vmcnt(4) + 2 raw s_barriers, P in-register, no max tracking).
// ---------------------------------------------------------------------------
__device__ __forceinline__ void attn_body(
    int blk, int tid,
    const float* __restrict__ q, const __bf16* __restrict__ kswz,
    const __bf16* __restrict__ vtswz, const float* __restrict__ pk,
    float* __restrict__ out, char* smem) {
  const int bh = blk >> 6, m = blk & 63;
  const int lane = tid & 63;
  const int w = tid >> 6;
  const int l16 = lane & 15, lhi = lane >> 4;

  __bf16 (*KV)[8192] = reinterpret_cast<__bf16(*)[8192]>(smem);
  float (*s_qf)[68] = reinterpret_cast<float(*)[68]>(smem);           // 17408 B
  float* bufq  = reinterpret_cast<float*>(smem + 17408);              // 1024 B
  float (*s_pk)[65] = reinterpret_cast<float(*)[65]>(smem);           // 16640 B
  float* s_pqr = reinterpret_cast<float*>(smem + 16640);              // 256 B
  float* s_km  = reinterpret_cast<float*>(smem + 16896);              // 256 B
  float* s_sc  = reinterpret_cast<float*>(smem + 17152);              // 256 B
  int*   s_lut = reinterpret_cast<int*>(smem + 18432);                // 64 B

  const size_t base = (size_t)bh * L_ * D_;

  // ---- Q B-fragments (hoisted: global loads hide under prologue) ----
  const float QSC = 0.125f * 1.44269504088896340736f;
  bf16x8 qf[2];
  {
    const float* qrow = q + base + (size_t)(m * 64 + w * 16 + l16) * D_;
#pragma unroll
    for (int s = 0; s < 2; s++) {
      const float* p0 = qrow + s * 32 + lhi * 8;
      float4 a = *(const float4*)p0;
      float4 b = *(const float4*)(p0 + 4);
      bf16x8 f;
      f[0] = (__bf16)(a.x * QSC); f[1] = (__bf16)(a.y * QSC);
      f[2] = (__bf16)(a.z * QSC); f[3] = (__bf16)(a.w * QSC);
      f[4] = (__bf16)(b.x * QSC); f[5] = (__bf16)(b.y * QSC);
      f[6] = (__bf16)(b.z * QSC); f[7] = (__bf16)(b.w * QSC);
      qf[s] = f;
    }
  }

  // ---- prologue A: pq row m from q (block_means' exact order) ----
  {
    const float* qsrc = q + base + (size_t)(m * 64) * D_;
    const int r = tid >> 2, c = (tid & 3) * 16;
    const float* qs = qsrc + r * 64 + c;
#pragma unroll
    for (int h = 0; h < 4; h++)
      *(float4*)&s_qf[r][c + h * 4] = *(const float4*)(qs + h * 4);
  }
  __syncthreads();
  {
    const int d = tid & 63, g = tid >> 6;
    float sq = 0.f;
#pragma unroll
    for (int i = 0; i < 16; i++) sq += s_qf[g * 16 + i][d];
    bufq[g * 64 + d] = sq;
  }
  __syncthreads();
  if (tid < 64) {   // g==0
    float tq = bufq[0 * 64 + tid] + bufq[1 * 64 + tid] + bufq[2 * 64 + tid] + bufq[3 * 64 + tid];
    s_pqr[tid] = tq * (1.f / 64.f);
  }
  __syncthreads();

  // ---- prologue B: blockmap selection for row m (EXACT replication) ----
  {
    const float* pkb = pk + (size_t)bh * 4096;
#pragma unroll
    for (int i = 0; i < 16; i++) {
      int idx = i * 256 + tid;
      s_pk[idx >> 6][idx & 63] = pkb[idx];
    }
    __syncthreads();
    if (tid < 64) {
      float s = 0.f;
#pragma unroll 8
      for (int r = 0; r < 64; r++) s += s_pk[r][tid];
      s_km[tid] = s * (1.f / 64.f);
    }
    __syncthreads();
    float sc = 0.f;
#pragma unroll 8
    for (int d2 = 0; d2 < 64; ++d2)
      sc += s_pqr[d2] * (s_pk[lane][d2] - s_km[d2]);
    s_sc[lane] = sc;
    __syncthreads();
    int rank = 0;
#pragma unroll 8
    for (int j = 0; j < 64; j++) {
      float o = s_sc[j];
      rank += (o > sc) || (o == sc && j < lane);
    }
    if (rank < TOPK_) s_lut[rank] = lane;
    __syncthreads();
  }
  const int myk = s_lut[lane & 15];   // LUT -> registers
  __syncthreads();                    // all s_lut reads done; smem free

  const __bf16* kimg = kswz + (size_t)bh * 64 * 4096;
  const __bf16* vbase = vtswz + (size_t)bh * 64 * 4096;

  auto stage = [&](int b, int kb) {
    const __bf16* gk = kimg + (size_t)kb * 4096;
    const __bf16* gv = vbase + (size_t)kb * 4096;
    async_copy16(&KV[b][0 * 2048 + w * 512], gk + 0 * 2048 + tid * 8);
    async_copy16(&KV[b][1 * 2048 + w * 512], gk + 1 * 2048 + tid * 8);
    async_copy16(&KV[b][4096 + 0 * 2048 + w * 512], gv + 0 * 2048 + tid * 8);
    async_copy16(&KV[b][4096 + 1 * 2048 + w * 512], gv + 1 * 2048 + tid * 8);
  };

  stage(0, __shfl(myk, 0, 64));

  f32x4 acc_o[4];
#pragma unroll
  for (int i = 0; i < 4; i++) acc_o[i] = (f32x4){0.f, 0.f, 0.f, 0.f};
  float l_run = 0.f;

  for (int it = 0; it < TOPK_; ++it) {
    const int cur = it & 1;
    if (it + 1 < TOPK_) {
      stage(cur ^ 1, __shfl(myk, it + 1, 64));
      asm volatile("s_waitcnt vmcnt(4)" ::: "memory");   // stage(it) landed
    } else {
      asm volatile("s_waitcnt vmcnt(0)" ::: "memory");
    }
    __builtin_amdgcn_s_barrier();          // B1: everyone's stage(it) complete
    __builtin_amdgcn_sched_barrier(0);     // nothing crosses upward

    const __bf16* Kl = &KV[cur][0];
    const __bf16* Vt = &KV[cur][4096];

    // ---- S^T = K @ Q^T (log2 units): accs[ct][r] = S[16ct+4lhi+r][l16] ----
    f32x4 accs[4];
#pragma unroll
    for (int x = 0; x < 4; x++) accs[x] = (f32x4){0.f, 0.f, 0.f, 0.f};
    __builtin_amdgcn_s_setprio(1);
#pragma unroll
    for (int ct = 0; ct < 4; ct++) {
      const int key = ct * 16 + l16;
#pragma unroll
      for (int s = 0; s < 2; s++) {
        const int c8 = s * 4 + lhi;
        bf16x8 bk = *(const bf16x8*)&Kl[key * 64 + ((c8 ^ (key & 7)) << 3)];
        accs[ct] = __builtin_amdgcn_mfma_f32_16x16x32_bf16(bk, qf[s], accs[ct], 0, 0, 0);
      }
    }
    __builtin_amdgcn_s_setprio(0);

    // ---- P = exp2(S) straight into PV A-fragments (no max tracking) ----
    bf16x8 pa0, pa1;
    float ls0 = 0.f, ls1 = 0.f;
#pragma unroll
    for (int j = 0; j < 8; j++) {
      float e0 = EXP2(accs[(j >> 2)][j & 3]);
      float e1 = EXP2(accs[2 + (j >> 2)][j & 3]);
      pa0[j] = (__bf16)e0; pa1[j] = (__bf16)e1;
      ls0 += e0; ls1 += e1;
    }
    l_run += ls0 + ls1;

    // ---- O += P @ V (V-image columns kpos-ordered, XOR-swizzled) ----
    __builtin_amdgcn_s_setprio(1);
#pragma unroll
    for (int s2 = 0; s2 < 2; s2++) {
      const int c8 = s2 * 4 + lhi;
      const bf16x8 pa = s2 ? pa1 : pa0;
#pragma unroll
      for (int ct2 = 0; ct2 < 4; ct2++) {
        const int d = ct2 * 16 + l16;
        bf16x8 bv = *(const bf16x8*)&Vt[d * 64 + ((c8 ^ (d & 7)) << 3)];
        acc_o[ct2] = __builtin_amdgcn_mfma_f32_16x16x32_bf16(pa, bv, acc_o[ct2], 0, 0, 0);
      }
    }
    __builtin_amdgcn_s_setprio(0);

    __builtin_amdgcn_s_barrier();          // B2: all reads of buf[cur] done
  }

  // ---- epilogue ----
  l_run += __shfl_xor(l_run, 16, 64);
  l_run += __shfl_xor(l_run, 32, 64);
  float rq[4];
#pragma unroll
  for (int r = 0; r < 4; r++)
    rq[r] = 1.f / __shfl(l_run, (lane & 48) | (lhi * 4 + r), 64);

  float* ob = out + base + (size_t)(m * 64 + w * 16) * D_;
#pragma unroll
  for (int ct2 = 0; ct2 < 4; ct2++) {
#pragma unroll
    for (int r = 0; r < 4; r++) {
      const int row = lhi * 4 + r, col = ct2 * 16 + l16;
      ob[(size_t)row * D_ + col] = acc_o[ct2][r] * rq[r];
    }
  }
}

// ---------------------------------------------------------------------------
// Fast path: two kernels (R14-equivalent; cooperative fusion measured 5.6x
// WORSE on gfx950 -- grid.sync() is a slow spin protocol at 1024 blocks).
// ---------------------------------------------------------------------------
__global__ __launch_bounds__(256) void prep_kernel2(
    const float* __restrict__ k, const float* __restrict__ v,
    float* __restrict__ pk, __bf16* __restrict__ kswz,
    __bf16* __restrict__ vtswz) {
  __shared__ __align__(16) char smem[32768];
  prep_body(blockIdx.x, threadIdx.x, k, v, pk, kswz, vtswz, smem);
}

__global__ __launch_bounds__(256, 5) void attn_kernel2(
    const float* __restrict__ q, const __bf16* __restrict__ kswz,
    const __bf16* __restrict__ vtswz, const float* __restrict__ pk,
    float* __restrict__ out) {
  __shared__ __align__(16) char smem[32768];
  const int bid = blockIdx.x;
  const int blk = (bid & 7) * 128 + (bid >> 3);   // T1 XCD swizzle
  attn_body(blk, threadIdx.x, q, kswz, vtswz, pk, out, smem);
}

// ---------------------------------------------------------------------------
// Slow fallback (ws too small): round-2 versions.
// ---------------------------------------------------------------------------
__global__ __launch_bounds__(256) void block_means_kernel(
    const float* __restrict__ q, const float* __restrict__ k,
    float* __restrict__ pq, float* __restrict__ pk) {
  const int blk = blockIdx.x;
  const int bh = blk >> 6, m = blk & 63;
  const int d = threadIdx.x & 63, g = threadIdx.x >> 6;
  const float* qb = q + ((size_t)bh * L_ + m * 64 + g * 16) * D_ + d;
  const float* kb = k + ((size_t)bh * L_ + m * 64 + g * 16) * D_ + d;
  float sq = 0.f, sk = 0.f;
#pragma unroll
  for (int i = 0; i < 16; i++) { sq += qb[(size_t)i * D_]; sk += kb[(size_t)i * D_]; }
  __shared__ float bufq[4][64];
  __shared__ float bufk[4][64];
  bufq[g][d] = sq; bufk[g][d] = sk;
  __syncthreads();
  if (g == 0) {
    float tq = bufq[0][d] + bufq[1][d] + bufq[2][d] + bufq[3][d];
    float tk = bufk[0][d] + bufk[1][d] + bufk[2][d] + bufk[3][d];
    pq[(size_t)blk * 64 + d] = tq * (1.f / 64.f);
    pk[(size_t)blk * 64 + d] = tk * (1.f / 64.f);
  }
}

__global__ __launch_bounds__(256) void blockmap_kernel(
    const float* __restrict__ pq, const float* __restrict__ pk,
    int* __restrict__ lut) {
  const int g = blockIdx.x;
  const int bh = g >> 2, q4 = g & 3;
  const int t = threadIdx.x;
  const int lane = t & 63, w = t >> 6;

  __shared__ float s_pk[64][65];
  __shared__ float s_km[64];
  __shared__ float s_pq[16][64];
  __shared__ float s_sc[4][64];

#pragma unroll
  for (int i = 0; i < 16; i++) {
    int idx = i * 256 + t;
    s_pk[idx >> 6][idx & 63] = pk[(size_t)bh * 4096 + idx];
  }
#pragma unroll
  for (int i = 0; i < 4; i++) {
    int idx = i * 256 + t;
    s_pq[idx >> 6][idx & 63] = pq[(size_t)bh * 4096 + q4 * 1024 + idx];
  }
  __syncthreads();
  if (t < 64) {
    float s = 0.f;
#pragma unroll 8
    for (int r = 0; r < 64; r++) s += s_pk[r][t];
    s_km[t] = s * (1.f / 64.f);
  }
  __syncthreads();

#pragma unroll
  for (int rr = 0; rr < 4; rr++) {
    const int row = w * 4 + rr;
    float sc = 0.f;
#pragma unroll 8
    for (int d2 = 0; d2 < 64; ++d2)
      sc += s_pq[row][d2] * (s_pk[lane][d2] - s_km[d2]);
    s_sc[w][lane] = sc;
    __syncthreads();
    int rank = 0;
#pragma unroll 8
    for (int j = 0; j < 64; j++) {
      float o = s_sc[w][j];
      rank += (o > sc) || (o == sc && j < lane);
    }
    if (rank < TOPK_)
      lut[((size_t)bh * 64 + q4 * 16 + row) * TOPK_ + rank] = lane;
    __syncthreads();
  }
}

__global__ __launch_bounds__(256) void sparse_attn_slow(
    const float* __restrict__ q, const float* __restrict__ k,
    const float* __restrict__ v, const int* __restrict__ lut,
    float* __restrict__ out) {
  const int blk = blockIdx.x;
  const int bh = blk >> 6, m = blk & 63;
  const int tid = threadIdx.x;
  const int lane = tid & 63;
  const int w = tid >> 6;
  const int l16 = lane & 15, lhi = lane >> 4;

  __shared__ __align__(16) __bf16 Kl[64 * 64];
  __shared__ __align__(16) __bf16 Vt[64 * 64];
  __shared__ __align__(16) __bf16 Pl[4][16 * 64];

  const size_t base = (size_t)bh * L_ * D_;

  bf16x8 qf[2];
  {
    const float* qrow = q + base + (size_t)(m * 64 + w * 16 + l16) * D_;
#pragma unroll
    for (int s = 0; s < 2; s++) {
      const float* p0 = qrow + s * 32 + lhi * 8;
      float4 a = *(const float4*)p0;
      float4 b = *(const float4*)(p0 + 4);
      bf16x8 f;
      f[0] = (__bf16)(a.x * 0.125f); f[1] = (__bf16)(a.y * 0.125f);
      f[2] = (__bf16)(a.z * 0.125f); f[3] = (__bf16)(a.w * 0.125f);
      f[4] = (__bf16)(b.x * 0.125f); f[5] = (__bf16)(b.y * 0.125f);
      f[6] = (__bf16)(b.z * 0.125f); f[7] = (__bf16)(b.w * 0.125f);
      qf[s] = f;
    }
  }

  f32x4 acc_o[4];
#pragma unroll
  for (int i = 0; i < 4; i++) acc_o[i] = (f32x4){0.f, 0.f, 0.f, 0.f};
  float m_run[4] = {-__builtin_inff(), -__builtin_inff(), -__builtin_inff(), -__builtin_inff()};
  float l_run[4] = {0.f, 0.f, 0.f, 0.f};

  const int srow = tid >> 2;
  const int sc16 = (tid & 3) * 16;

  for (int it = 0; it < TOPK_; ++it) {
    const int kb = lut[(size_t)blk * TOPK_ + it];
    __syncthreads();
    {
      const float* ks = k + base + (size_t)(kb * 64 + srow) * D_ + sc16;
      const float* vs = v + base + (size_t)(kb * 64 + srow) * D_ + sc16;
      float kf[16], vf[16];
#pragma unroll
      for (int h = 0; h < 4; h++) {
        float4 t4 = *(const float4*)(ks + h * 4);
        kf[h * 4 + 0] = t4.x; kf[h * 4 + 1] = t4.y; kf[h * 4 + 2] = t4.z; kf[h * 4 + 3] = t4.w;
        float4 u4 = *(const float4*)(vs + h * 4);
        vf[h * 4 + 0] = u4.x; vf[h * 4 + 1] = u4.y; vf[h * 4 + 2] = u4.z; vf[h * 4 + 3] = u4.w;
      }
#pragma unroll
      for (int h = 0; h < 2; h++) {
        int c8 = (sc16 >> 3) + h;
        bf16x8 kw;
#pragma unroll
        for (int j = 0; j < 8; j++) kw[j] = (__bf16)kf[h * 8 + j];
        *(bf16x8*)&Kl[srow * 64 + ((c8 ^ (srow & 7)) << 3)] = kw;
      }
#pragma unroll
      for (int i = 0; i < 16; i++) {
        int d = sc16 + i;
        Vt[d * 64 + (srow ^ ((d & 7) << 3))] = (__bf16)vf[i];
      }
    }
    __syncthreads();

    f32x4 accs[4];
#pragma unroll
    for (int i = 0; i < 4; i++) accs[i] = (f32x4){0.f, 0.f, 0.f, 0.f};
#pragma unroll
    for (int ct = 0; ct < 4; ct++) {
      const int key = ct * 16 + l16;
#pragma unroll
      for (int s = 0; s < 2; s++) {
        const int c8 = s * 4 + lhi;
        bf16x8 bk = *(const bf16x8*)&Kl[key * 64 + ((c8 ^ (key & 7)) << 3)];
        accs[ct] = __builtin_amdgcn_mfma_f32_16x16x32_bf16(qf[s], bk, accs[ct], 0, 0, 0);
      }
    }

    float pvals[4][4];
#pragma unroll
    for (int r = 0; r < 4; r++) {
      float mx = fmaxf(fmaxf(accs[0][r], accs[1][r]), fmaxf(accs[2][r], accs[3][r]));
#pragma unroll
      for (int off = 1; off < 16; off <<= 1) mx = fmaxf(mx, __shfl_xor(mx, off, 64));
      const float mnew = fmaxf(m_run[r], mx);
      const float scale = __expf(m_run[r] - mnew);
      float rs = 0.f;
#pragma unroll
      for (int ct = 0; ct < 4; ct++) {
        float e = __expf(accs[ct][r] - mnew);
        pvals[ct][r] = e; rs += e;
      }
#pragma unroll
      for (int off = 1; off < 16; off <<= 1) rs += __shfl_xor(rs, off, 64);
      l_run[r] = l_run[r] * scale + rs;
      m_run[r] = mnew;
#pragma unroll
      for (int ct = 0; ct < 4; ct++) acc_o[ct][r] *= scale;
    }

#pragma unroll
    for (int ct = 0; ct < 4; ct++) {
#pragma unroll
      for (int r = 0; r < 4; r++) {
        const int row = lhi * 4 + r, col = ct * 16 + l16;
        Pl[w][row * 64 + (col ^ ((row & 7) << 3))] = (__bf16)pvals[ct][r];
      }
    }
#pragma unroll
    for (int s = 0; s < 2; s++) {
      const int c8 = s * 4 + lhi;
      bf16x8 pa = *(const bf16x8*)&Pl[w][l16 * 64 + ((c8 ^ (l16 & 7)) << 3)];
#pragma unroll
      for (int ct2 = 0; ct2 < 4; ct2++) {
        const int d = ct2 * 16 + l16;
        bf16x8 bv = *(const bf16x8*)&Vt[d * 64 + ((c8 ^ (d & 7)) << 3)];
        acc_o[ct2] = __builtin_amdgcn_mfma_f32_16x16x32_bf16(pa, bv, acc_o[ct2], 0, 0, 0);
      }
    }
  }

  float* ob = out + base + (size_t)(m * 64 + w * 16) * D_;
#pragma unroll
  for (int ct2 = 0; ct2 < 4; ct2++) {
#pragma unroll
    for (int r = 0; r < 4; r++) {
      const int row = lhi * 4 + r, col = ct2 * 16 + l16;
      ob[(size_t)row * D_ + col] = acc_o[ct2][r] / l_run[r];
    }
  }
}

extern "C" void kernel_launch(void* const* d_in, const int* in_sizes, int n_in,
                              void* d_out, int out_size, void* d_ws, size_t ws_size,
                              hipStream_t stream) {
  const float* q = (const float*)d_in[0];
  const float* k = (const float*)d_in[1];
  const float* v = (const float*)d_in[2];
  float* out = (float*)d_out;

  // ws layout: pq (256KB) | pk (256KB) | lut (64KB) | Kswz (8MB) | Vtswz (8MB)
  float* pq = (float*)d_ws;
  float* pk = pq + (size_t)BH_ * NB_ * D_;
  int*   lut = (int*)(pk + (size_t)BH_ * NB_ * D_);
  char*  extra = (char*)(lut + (size_t)BH_ * NB_ * TOPK_);
  __bf16* kswz = (__bf16*)extra;
  __bf16* vtswz = kswz + (size_t)BH_ * NB_ * 4096;

  const size_t needed = (size_t)((char*)(vtswz + (size_t)BH_ * NB_ * 4096) - (char*)d_ws);
  const bool fast = ws_size >= needed;

  if (fast) {
    hipLaunchKernelGGL(prep_kernel2, dim3(BH_ * NB_), dim3(256), 0, stream,
                       k, v, pk, kswz, vtswz);
    hipLaunchKernelGGL(attn_kernel2, dim3(BH_ * NB_), dim3(256), 0, stream,
                       q, kswz, vtswz, pk, out);
  } else {
    hipLaunchKernelGGL(block_means_kernel, dim3(BH_ * NB_), dim3(256), 0, stream, q, k, pq, pk);
    hipLaunchKernelGGL(blockmap_kernel, dim3(BH_ * 4), dim3(256), 0, stream, pq, pk, lut);
    hipLaunchKernelGGL(sparse_attn_slow, dim3(BH_ * NB_), dim3(256), 0, stream, q, k, v, lut, out);
  }
}

// Round 17
// 44.030 us; speedup vs baseline: 5.6614x; 1.0146x over previous
//
#include <hip/hip_runtime.h>
#include <hip/hip_bf16.h>

#define B_ 2
#define H_ 8
#define L_ 4096
#define D_ 64
#define NB_ 64
#define TOPK_ 16
#define BH_ 16

typedef __bf16 bf16x8 __attribute__((ext_vector_type(8)));
typedef float f32x4 __attribute__((ext_vector_type(4)));

#if __has_builtin(__builtin_amdgcn_exp2f)
#define EXP2(x) __builtin_amdgcn_exp2f(x)
#else
#define EXP2(x) exp2f(x)
#endif

__device__ __forceinline__ void async_copy16(void* lds, const void* g) {
  __builtin_amdgcn_global_load_lds(
      (const __attribute__((address_space(1))) void*)g,
      (__attribute__((address_space(3))) void*)lds, 16, 0, 0);
}

// ---------------------------------------------------------------------------
// prep_body: k-image (R8 XOR-swizzled) + k block mean (block_means' exact
// layout & summation order -> pk bit-identical) + v-image (V^T, kpos-
// permuted, XOR-swizzled).  One source block per call.
// ---------------------------------------------------------------------------
__device__ __forceinline__ void prep_body(
    int blk, int tid,
    const float* __restrict__ k, const float* __restrict__ v,
    float* __restrict__ pk, __bf16* __restrict__ kswz,
    __bf16* __restrict__ vtswz, char* smem) {
  float (*s_kf)[64] = reinterpret_cast<float(*)[64]>(smem);          // 16384 B
  float* bufk = reinterpret_cast<float*>(smem + 16384);              // 1024 B
  __bf16* s_vt = reinterpret_cast<__bf16*>(smem + 17408);            // 8192 B

  const int srow = tid >> 2;           // key row 0..63
  const int sc16 = (tid & 3) * 16;     // d col base

  const float* ks = k + (size_t)blk * 4096 + srow * 64 + sc16;
  const float* vs = v + (size_t)blk * 4096 + srow * 64 + sc16;
  float kf[16], vf[16];
#pragma unroll
  for (int h = 0; h < 4; h++) {
    float4 t4 = *(const float4*)(ks + h * 4);
    kf[h * 4 + 0] = t4.x; kf[h * 4 + 1] = t4.y; kf[h * 4 + 2] = t4.z; kf[h * 4 + 3] = t4.w;
    *(float4*)&s_kf[srow][sc16 + h * 4] = t4;
  }
#pragma unroll
  for (int h = 0; h < 4; h++) {
    float4 u4 = *(const float4*)(vs + h * 4);
    vf[h * 4 + 0] = u4.x; vf[h * 4 + 1] = u4.y; vf[h * 4 + 2] = u4.z; vf[h * 4 + 3] = u4.w;
  }

  __bf16* gk = kswz + (size_t)blk * 4096;
#pragma unroll
  for (int h = 0; h < 2; h++) {
    int c8 = (sc16 >> 3) + h;
    bf16x8 kw;
#pragma unroll
    for (int j = 0; j < 8; j++) kw[j] = (__bf16)kf[h * 8 + j];
    *(bf16x8*)(gk + srow * 64 + ((c8 ^ (srow & 7)) << 3)) = kw;
  }

  const int kpos = (srow & 32) + ((srow >> 2) & 3) * 8 + ((srow >> 4) & 1) * 4 + (srow & 3);
#pragma unroll
  for (int i = 0; i < 16; i++) {
    int d = sc16 + i;
    s_vt[d * 64 + (kpos ^ ((d & 7) << 3))] = (__bf16)vf[i];
  }
  __syncthreads();

  // k mean: thread (d,g) sums rows g*16+i sequentially (block_means order)
  const int d = tid & 63, g = tid >> 6;
  float sk = 0.f;
#pragma unroll
  for (int i = 0; i < 16; i++) sk += s_kf[g * 16 + i][d];
  bufk[g * 64 + d] = sk;

  // v image copy-out (s_vt ready after the sync above)
  __bf16* gv = vtswz + (size_t)blk * 4096;
  *(bf16x8*)(gv + tid * 8)        = *(const bf16x8*)(s_vt + tid * 8);
  *(bf16x8*)(gv + 2048 + tid * 8) = *(const bf16x8*)(s_vt + 2048 + tid * 8);

  __syncthreads();
  if (g == 0) {
    float tk = bufk[0 * 64 + d] + bufk[1 * 64 + d] + bufk[2 * 64 + d] + bufk[3 * 64 + d];
    pk[(size_t)blk * 64 + d] = tk * (1.f / 64.f);
  }
}

// ---------------------------------------------------------------------------
// attn_body: prologue A (q-mean, block_means' exact order), prologue B
// (blockmap selection, exact replication), main loop (KV LDS double-buffer,
// counted vmcnt(4) + 2 raw s_barriers, P in-register, no max tracking).
// ---------------------------------------------------------------------------
__device__ __forceinline__ void attn_body(
    int blk, int tid,
    const float* __restrict__ q, const __bf16* __restrict__ kswz,
    const __bf16* __restrict__ vtswz, const float* __restrict__ pk,
    float* __restrict__ out, char* smem) {
  const int bh = blk >> 6, m = blk & 63;
  const int lane = tid & 63;
  const int w = tid >> 6;
  const int l16 = lane & 15, lhi = lane >> 4;

  __bf16 (*KV)[8192] = reinterpret_cast<__bf16(*)[8192]>(smem);
  float (*s_qf)[68] = reinterpret_cast<float(*)[68]>(smem);           // 17408 B
  float* bufq  = reinterpret_cast<float*>(smem + 17408);              // 1024 B
  float (*s_pk)[65] = reinterpret_cast<float(*)[65]>(smem);           // 16640 B
  float* s_pqr = reinterpret_cast<float*>(smem + 16640);              // 256 B
  float* s_km  = reinterpret_cast<float*>(smem + 16896);              // 256 B
  float* s_sc  = reinterpret_cast<float*>(smem + 17152);              // 256 B
  int*   s_lut = reinterpret_cast<int*>(smem + 18432);                // 64 B

  const size_t base = (size_t)bh * L_ * D_;

  // ---- Q B-fragments (hoisted: global loads hide under prologue) ----
  const float QSC = 0.125f * 1.44269504088896340736f;
  bf16x8 qf[2];
  {
    const float* qrow = q + base + (size_t)(m * 64 + w * 16 + l16) * D_;
#pragma unroll
    for (int s = 0; s < 2; s++) {
      const float* p0 = qrow + s * 32 + lhi * 8;
      float4 a = *(const float4*)p0;
      float4 b = *(const float4*)(p0 + 4);
      bf16x8 f;
      f[0] = (__bf16)(a.x * QSC); f[1] = (__bf16)(a.y * QSC);
      f[2] = (__bf16)(a.z * QSC); f[3] = (__bf16)(a.w * QSC);
      f[4] = (__bf16)(b.x * QSC); f[5] = (__bf16)(b.y * QSC);
      f[6] = (__bf16)(b.z * QSC); f[7] = (__bf16)(b.w * QSC);
      qf[s] = f;
    }
  }

  // ---- prologue A: pq row m from q (block_means' exact order) ----
  {
    const float* qsrc = q + base + (size_t)(m * 64) * D_;
    const int r = tid >> 2, c = (tid & 3) * 16;
    const float* qs = qsrc + r * 64 + c;
#pragma unroll
    for (int h = 0; h < 4; h++)
      *(float4*)&s_qf[r][c + h * 4] = *(const float4*)(qs + h * 4);
  }
  __syncthreads();
  {
    const int d = tid & 63, g = tid >> 6;
    float sq = 0.f;
#pragma unroll
    for (int i = 0; i < 16; i++) sq += s_qf[g * 16 + i][d];
    bufq[g * 64 + d] = sq;
  }
  __syncthreads();
  if (tid < 64) {   // g==0
    float tq = bufq[0 * 64 + tid] + bufq[1 * 64 + tid] + bufq[2 * 64 + tid] + bufq[3 * 64 + tid];
    s_pqr[tid] = tq * (1.f / 64.f);
  }
  __syncthreads();

  // ---- prologue B: blockmap selection for row m (EXACT replication) ----
  {
    const float* pkb = pk + (size_t)bh * 4096;
#pragma unroll
    for (int i = 0; i < 16; i++) {
      int idx = i * 256 + tid;
      s_pk[idx >> 6][idx & 63] = pkb[idx];
    }
    __syncthreads();
    if (tid < 64) {
      float s = 0.f;
#pragma unroll 8
      for (int r = 0; r < 64; r++) s += s_pk[r][tid];
      s_km[tid] = s * (1.f / 64.f);
    }
    __syncthreads();
    float sc = 0.f;
#pragma unroll 8
    for (int d2 = 0; d2 < 64; ++d2)
      sc += s_pqr[d2] * (s_pk[lane][d2] - s_km[d2]);
    s_sc[lane] = sc;
    __syncthreads();
    int rank = 0;
#pragma unroll 8
    for (int j = 0; j < 64; j++) {
      float o = s_sc[j];
      rank += (o > sc) || (o == sc && j < lane);
    }
    if (rank < TOPK_) s_lut[rank] = lane;
    __syncthreads();
  }
  const int myk = s_lut[lane & 15];   // LUT -> registers
  __syncthreads();                    // all s_lut reads done; smem free

  const __bf16* kimg = kswz + (size_t)bh * 64 * 4096;
  const __bf16* vbase = vtswz + (size_t)bh * 64 * 4096;

  auto stage = [&](int b, int kb) {
    const __bf16* gk = kimg + (size_t)kb * 4096;
    const __bf16* gv = vbase + (size_t)kb * 4096;
    async_copy16(&KV[b][0 * 2048 + w * 512], gk + 0 * 2048 + tid * 8);
    async_copy16(&KV[b][1 * 2048 + w * 512], gk + 1 * 2048 + tid * 8);
    async_copy16(&KV[b][4096 + 0 * 2048 + w * 512], gv + 0 * 2048 + tid * 8);
    async_copy16(&KV[b][4096 + 1 * 2048 + w * 512], gv + 1 * 2048 + tid * 8);
  };

  stage(0, __shfl(myk, 0, 64));

  f32x4 acc_o[4];
#pragma unroll
  for (int i = 0; i < 4; i++) acc_o[i] = (f32x4){0.f, 0.f, 0.f, 0.f};
  float l_run = 0.f;

  for (int it = 0; it < TOPK_; ++it) {
    const int cur = it & 1;
    if (it + 1 < TOPK_) {
      stage(cur ^ 1, __shfl(myk, it + 1, 64));
      asm volatile("s_waitcnt vmcnt(4)" ::: "memory");   // stage(it) landed
    } else {
      asm volatile("s_waitcnt vmcnt(0)" ::: "memory");
    }
    __builtin_amdgcn_s_barrier();          // B1: everyone's stage(it) complete
    __builtin_amdgcn_sched_barrier(0);     // nothing crosses upward

    const __bf16* Kl = &KV[cur][0];
    const __bf16* Vt = &KV[cur][4096];

    // ---- S^T = K @ Q^T (log2 units): accs[ct][r] = S[16ct+4lhi+r][l16] ----
    f32x4 accs[4];
#pragma unroll
    for (int x = 0; x < 4; x++) accs[x] = (f32x4){0.f, 0.f, 0.f, 0.f};
    __builtin_amdgcn_s_setprio(1);
#pragma unroll
    for (int ct = 0; ct < 4; ct++) {
      const int key = ct * 16 + l16;
#pragma unroll
      for (int s = 0; s < 2; s++) {
        const int c8 = s * 4 + lhi;
        bf16x8 bk = *(const bf16x8*)&Kl[key * 64 + ((c8 ^ (key & 7)) << 3)];
        accs[ct] = __builtin_amdgcn_mfma_f32_16x16x32_bf16(bk, qf[s], accs[ct], 0, 0, 0);
      }
    }
    __builtin_amdgcn_s_setprio(0);

    // ---- P = exp2(S) straight into PV A-fragments (no max tracking) ----
    bf16x8 pa0, pa1;
    float ls0 = 0.f, ls1 = 0.f;
#pragma unroll
    for (int j = 0; j < 8; j++) {
      float e0 = EXP2(accs[(j >> 2)][j & 3]);
      float e1 = EXP2(accs[2 + (j >> 2)][j & 3]);
      pa0[j] = (__bf16)e0; pa1[j] = (__bf16)e1;
      ls0 += e0; ls1 += e1;
    }
    l_run += ls0 + ls1;

    // ---- O += P @ V (V-image columns kpos-ordered, XOR-swizzled) ----
    __builtin_amdgcn_s_setprio(1);
#pragma unroll
    for (int s2 = 0; s2 < 2; s2++) {
      const int c8 = s2 * 4 + lhi;
      const bf16x8 pa = s2 ? pa1 : pa0;
#pragma unroll
      for (int ct2 = 0; ct2 < 4; ct2++) {
        const int d = ct2 * 16 + l16;
        bf16x8 bv = *(const bf16x8*)&Vt[d * 64 + ((c8 ^ (d & 7)) << 3)];
        acc_o[ct2] = __builtin_amdgcn_mfma_f32_16x16x32_bf16(pa, bv, acc_o[ct2], 0, 0, 0);
      }
    }
    __builtin_amdgcn_s_setprio(0);

    __builtin_amdgcn_s_barrier();          // B2: all reads of buf[cur] done
  }

  // ---- epilogue ----
  l_run += __shfl_xor(l_run, 16, 64);
  l_run += __shfl_xor(l_run, 32, 64);
  float rq[4];
#pragma unroll
  for (int r = 0; r < 4; r++)
    rq[r] = 1.f / __shfl(l_run, (lane & 48) | (lhi * 4 + r), 64);

  float* ob = out + base + (size_t)(m * 64 + w * 16) * D_;
#pragma unroll
  for (int ct2 = 0; ct2 < 4; ct2++) {
#pragma unroll
    for (int r = 0; r < 4; r++) {
      const int row = lhi * 4 + r, col = ct2 * 16 + l16;
      ob[(size_t)row * D_ + col] = acc_o[ct2][r] * rq[r];
    }
  }
}

// ---------------------------------------------------------------------------
// Fast path: two kernels.  BOTH use the same XCD swizzle so the prep block
// producing bh's images runs on the same XCD-L2 that attn's bh blocks read
// from (cross-XCD L2s are not shared -> aligning producer/consumer turns
// the image handoff into L2 hits).
// ---------------------------------------------------------------------------
__global__ __launch_bounds__(256) void prep_kernel2(
    const float* __restrict__ k, const float* __restrict__ v,
    float* __restrict__ pk, __bf16* __restrict__ kswz,
    __bf16* __restrict__ vtswz) {
  __shared__ __align__(16) char smem[32768];
  const int bid = blockIdx.x;
  const int blk = (bid & 7) * 128 + (bid >> 3);   // same swizzle as attn
  prep_body(blk, threadIdx.x, k, v, pk, kswz, vtswz, smem);
}

__global__ __launch_bounds__(256, 5) void attn_kernel2(
    const float* __restrict__ q, const __bf16* __restrict__ kswz,
    const __bf16* __restrict__ vtswz, const float* __restrict__ pk,
    float* __restrict__ out) {
  __shared__ __align__(16) char smem[32768];
  const int bid = blockIdx.x;
  const int blk = (bid & 7) * 128 + (bid >> 3);   // T1 XCD swizzle
  attn_body(blk, threadIdx.x, q, kswz, vtswz, pk, out, smem);
}

// ---------------------------------------------------------------------------
// Slow fallback (ws too small): round-2 versions.
// ---------------------------------------------------------------------------
__global__ __launch_bounds__(256) void block_means_kernel(
    const float* __restrict__ q, const float* __restrict__ k,
    float* __restrict__ pq, float* __restrict__ pk) {
  const int blk = blockIdx.x;
  const int bh = blk >> 6, m = blk & 63;
  const int d = threadIdx.x & 63, g = threadIdx.x >> 6;
  const float* qb = q + ((size_t)bh * L_ + m * 64 + g * 16) * D_ + d;
  const float* kb = k + ((size_t)bh * L_ + m * 64 + g * 16) * D_ + d;
  float sq = 0.f, sk = 0.f;
#pragma unroll
  for (int i = 0; i < 16; i++) { sq += qb[(size_t)i * D_]; sk += kb[(size_t)i * D_]; }
  __shared__ float bufq[4][64];
  __shared__ float bufk[4][64];
  bufq[g][d] = sq; bufk[g][d] = sk;
  __syncthreads();
  if (g == 0) {
    float tq = bufq[0][d] + bufq[1][d] + bufq[2][d] + bufq[3][d];
    float tk = bufk[0][d] + bufk[1][d] + bufk[2][d] + bufk[3][d];
    pq[(size_t)blk * 64 + d] = tq * (1.f / 64.f);
    pk[(size_t)blk * 64 + d] = tk * (1.f / 64.f);
  }
}

__global__ __launch_bounds__(256) void blockmap_kernel(
    const float* __restrict__ pq, const float* __restrict__ pk,
    int* __restrict__ lut) {
  const int g = blockIdx.x;
  const int bh = g >> 2, q4 = g & 3;
  const int t = threadIdx.x;
  const int lane = t & 63, w = t >> 6;

  __shared__ float s_pk[64][65];
  __shared__ float s_km[64];
  __shared__ float s_pq[16][64];
  __shared__ float s_sc[4][64];

#pragma unroll
  for (int i = 0; i < 16; i++) {
    int idx = i * 256 + t;
    s_pk[idx >> 6][idx & 63] = pk[(size_t)bh * 4096 + idx];
  }
#pragma unroll
  for (int i = 0; i < 4; i++) {
    int idx = i * 256 + t;
    s_pq[idx >> 6][idx & 63] = pq[(size_t)bh * 4096 + q4 * 1024 + idx];
  }
  __syncthreads();
  if (t < 64) {
    float s = 0.f;
#pragma unroll 8
    for (int r = 0; r < 64; r++) s += s_pk[r][t];
    s_km[t] = s * (1.f / 64.f);
  }
  __syncthreads();

#pragma unroll
  for (int rr = 0; rr < 4; rr++) {
    const int row = w * 4 + rr;
    float sc = 0.f;
#pragma unroll 8
    for (int d2 = 0; d2 < 64; ++d2)
      sc += s_pq[row][d2] * (s_pk[lane][d2] - s_km[d2]);
    s_sc[w][lane] = sc;
    __syncthreads();
    int rank = 0;
#pragma unroll 8
    for (int j = 0; j < 64; j++) {
      float o = s_sc[w][j];
      rank += (o > sc) || (o == sc && j < lane);
    }
    if (rank < TOPK_)
      lut[((size_t)bh * 64 + q4 * 16 + row) * TOPK_ + rank] = lane;
    __syncthreads();
  }
}

__global__ __launch_bounds__(256) void sparse_attn_slow(
    const float* __restrict__ q, const float* __restrict__ k,
    const float* __restrict__ v, const int* __restrict__ lut,
    float* __restrict__ out) {
  const int blk = blockIdx.x;
  const int bh = blk >> 6, m = blk & 63;
  const int tid = threadIdx.x;
  const int lane = tid & 63;
  const int w = tid >> 6;
  const int l16 = lane & 15, lhi = lane >> 4;

  __shared__ __align__(16) __bf16 Kl[64 * 64];
  __shared__ __align__(16) __bf16 Vt[64 * 64];
  __shared__ __align__(16) __bf16 Pl[4][16 * 64];

  const size_t base = (size_t)bh * L_ * D_;

  bf16x8 qf[2];
  {
    const float* qrow = q + base + (size_t)(m * 64 + w * 16 + l16) * D_;
#pragma unroll
    for (int s = 0; s < 2; s++) {
      const float* p0 = qrow + s * 32 + lhi * 8;
      float4 a = *(const float4*)p0;
      float4 b = *(const float4*)(p0 + 4);
      bf16x8 f;
      f[0] = (__bf16)(a.x * 0.125f); f[1] = (__bf16)(a.y * 0.125f);
      f[2] = (__bf16)(a.z * 0.125f); f[3] = (__bf16)(a.w * 0.125f);
      f[4] = (__bf16)(b.x * 0.125f); f[5] = (__bf16)(b.y * 0.125f);
      f[6] = (__bf16)(b.z * 0.125f); f[7] = (__bf16)(b.w * 0.125f);
      qf[s] = f;
    }
  }

  f32x4 acc_o[4];
#pragma unroll
  for (int i = 0; i < 4; i++) acc_o[i] = (f32x4){0.f, 0.f, 0.f, 0.f};
  float m_run[4] = {-__builtin_inff(), -__builtin_inff(), -__builtin_inff(), -__builtin_inff()};
  float l_run[4] = {0.f, 0.f, 0.f, 0.f};

  const int srow = tid >> 2;
  const int sc16 = (tid & 3) * 16;

  for (int it = 0; it < TOPK_; ++it) {
    const int kb = lut[(size_t)blk * TOPK_ + it];
    __syncthreads();
    {
      const float* ks = k + base + (size_t)(kb * 64 + srow) * D_ + sc16;
      const float* vs = v + base + (size_t)(kb * 64 + srow) * D_ + sc16;
      float kf[16], vf[16];
#pragma unroll
      for (int h = 0; h < 4; h++) {
        float4 t4 = *(const float4*)(ks + h * 4);
        kf[h * 4 + 0] = t4.x; kf[h * 4 + 1] = t4.y; kf[h * 4 + 2] = t4.z; kf[h * 4 + 3] = t4.w;
        float4 u4 = *(const float4*)(vs + h * 4);
        vf[h * 4 + 0] = u4.x; vf[h * 4 + 1] = u4.y; vf[h * 4 + 2] = u4.z; vf[h * 4 + 3] = u4.w;
      }
#pragma unroll
      for (int h = 0; h < 2; h++) {
        int c8 = (sc16 >> 3) + h;
        bf16x8 kw;
#pragma unroll
        for (int j = 0; j < 8; j++) kw[j] = (__bf16)kf[h * 8 + j];
        *(bf16x8*)&Kl[srow * 64 + ((c8 ^ (srow & 7)) << 3)] = kw;
      }
#pragma unroll
      for (int i = 0; i < 16; i++) {
        int d = sc16 + i;
        Vt[d * 64 + (srow ^ ((d & 7) << 3))] = (__bf16)vf[i];
      }
    }
    __syncthreads();

    f32x4 accs[4];
#pragma unroll
    for (int i = 0; i < 4; i++) accs[i] = (f32x4){0.f, 0.f, 0.f, 0.f};
#pragma unroll
    for (int ct = 0; ct < 4; ct++) {
      const int key = ct * 16 + l16;
#pragma unroll
      for (int s = 0; s < 2; s++) {
        const int c8 = s * 4 + lhi;
        bf16x8 bk = *(const bf16x8*)&Kl[key * 64 + ((c8 ^ (key & 7)) << 3)];
        accs[ct] = __builtin_amdgcn_mfma_f32_16x16x32_bf16(qf[s], bk, accs[ct], 0, 0, 0);
      }
    }

    float pvals[4][4];
#pragma unroll
    for (int r = 0; r < 4; r++) {
      float mx = fmaxf(fmaxf(accs[0][r], accs[1][r]), fmaxf(accs[2][r], accs[3][r]));
#pragma unroll
      for (int off = 1; off < 16; off <<= 1) mx = fmaxf(mx, __shfl_xor(mx, off, 64));
      const float mnew = fmaxf(m_run[r], mx);
      const float scale = __expf(m_run[r] - mnew);
      float rs = 0.f;
#pragma unroll
      for (int ct = 0; ct < 4; ct++) {
        float e = __expf(accs[ct][r] - mnew);
        pvals[ct][r] = e; rs += e;
      }
#pragma unroll
      for (int off = 1; off < 16; off <<= 1) rs += __shfl_xor(rs, off, 64);
      l_run[r] = l_run[r] * scale + rs;
      m_run[r] = mnew;
#pragma unroll
      for (int ct = 0; ct < 4; ct++) acc_o[ct][r] *= scale;
    }

#pragma unroll
    for (int ct = 0; ct < 4; ct++) {
#pragma unroll
      for (int r = 0; r < 4; r++) {
        const int row = lhi * 4 + r, col = ct * 16 + l16;
        Pl[w][row * 64 + (col ^ ((row & 7) << 3))] = (__bf16)pvals[ct][r];
      }
    }
#pragma unroll
    for (int s = 0; s < 2; s++) {
      const int c8 = s * 4 + lhi;
      bf16x8 pa = *(const bf16x8*)&Pl[w][l16 * 64 + ((c8 ^ (l16 & 7)) << 3)];
#pragma unroll
      for (int ct2 = 0; ct2 < 4; ct2++) {
        const int d = ct2 * 16 + l16;
        bf16x8 bv = *(const bf16x8*)&Vt[d * 64 + ((c8 ^ (d & 7)) << 3)];
        acc_o[ct2] = __builtin_amdgcn_mfma_f32_16x16x32_bf16(pa, bv, acc_o[ct2], 0, 0, 0);
      }
    }
  }

  float* ob = out + base + (size_t)(m * 64 + w * 16) * D_;
#pragma unroll
  for (int ct2 = 0; ct2 < 4; ct2++) {
#pragma unroll
    for (int r = 0; r < 4; r++) {
      const int row = lhi * 4 + r, col = ct2 * 16 + l16;
      ob[(size_t)row * D_ + col] = acc_o[ct2][r] / l_run[r];
    }
  }
}

extern "C" void kernel_launch(void* const* d_in, const int* in_sizes, int n_in,
                              void* d_out, int out_size, void* d_ws, size_t ws_size,
                              hipStream_t stream) {
  const float* q = (const float*)d_in[0];
  const float* k = (const float*)d_in[1];
  const float* v = (const float*)d_in[2];
  float* out = (float*)d_out;

  // ws layout: pq (256KB) | pk (256KB) | lut (64KB) | Kswz (8MB) | Vtswz (8MB)
  float* pq = (float*)d_ws;
  float* pk = pq + (size_t)BH_ * NB_ * D_;
  int*   lut = (int*)(pk + (size_t)BH_ * NB_ * D_);
  char*  extra = (char*)(lut + (size_t)BH_ * NB_ * TOPK_);
  __bf16* kswz = (__bf16*)extra;
  __bf16* vtswz = kswz + (size_t)BH_ * NB_ * 4096;

  const size_t needed = (size_t)((char*)(vtswz + (size_t)BH_ * NB_ * 4096) - (char*)d_ws);
  const bool fast = ws_size >= needed;

  if (fast) {
    hipLaunchKernelGGL(prep_kernel2, dim3(BH_ * NB_), dim3(256), 0, stream,
                       k, v, pk, kswz, vtswz);
    hipLaunchKernelGGL(attn_kernel2, dim3(BH_ * NB_), dim3(256), 0, stream,
                       q, kswz, vtswz, pk, out);
  } else {
    hipLaunchKernelGGL(block_means_kernel, dim3(BH_ * NB_), dim3(256), 0, stream, q, k, pq, pk);
    hipLaunchKernelGGL(blockmap_kernel, dim3(BH_ * 4), dim3(256), 0, stream, pq, pk, lut);
    hipLaunchKernelGGL(sparse_attn_slow, dim3(BH_ * NB_), dim3(256), 0, stream, q, k, v, lut, out);
  }
}